// Round 9
// baseline (150.481 us; speedup 1.0000x reference)
//
#include <hip/hip_runtime.h>

// NAVAR dims (fixed by the problem)
#define T_LEN   2048
#define BATCH   8
#define HIDDEN  16
#define KSZ     4
#define NVAR    12
#define NGROUPS 96      // ND*NS*NV = 2*4*12

// Wave-autonomous tiling: each WAVE owns 104 outputs + private 24-halo.
#define WOUT  104             // useful outputs per wave
#define WHALO 24              // 3*(1+1+2+4) receptive-field halo
#define WPOS  128             // positions computed per wave (2 x 64 lanes)
#define WPAD  16              // pad rows at ARRAY HEAD only (see hb note)
#define ROWCH 24              // 16 ch + 8 pad (48 B rows, 16-B aligned, 2-way banks)
#define NBT   5               // blocks along T (4 waves * 104 = 416; 5*416=2080)

#define NWH  (3 * NGROUPS * HIDDEN * HIDDEN * KSZ)   // 294912 hidden weights
#define NWO  (NGROUPS * HIDDEN * 32)                 // 49152 padded out weights

typedef __attribute__((ext_vector_type(8))) short bf16x8;   // MFMA A/B frag
typedef __attribute__((ext_vector_type(4))) float f32x4;    // MFMA C/D frag

__device__ __forceinline__ unsigned short f2bf(float x) {   // fp32 -> bf16 RNE
    union { float f; unsigned u; } v; v.f = x;
    unsigned r = v.u + 0x7FFFu + ((v.u >> 16) & 1u);
    return (unsigned short)(r >> 16);
}

// fp32 pair -> packed bf16x2 via HW RNE convert (same rounding as f2bf;
// verified R4/R5: absmax unchanged).
__device__ __forceinline__ unsigned cvtpk(float lo, float hi) {
    unsigned r;
    asm("v_cvt_pk_bf16_f32 %0, %1, %2" : "=v"(r) : "v"(lo), "v"(hi));
    return r;
}

// Wave-level LDS phase fence: memory clobber stops the compiler from
// per-lane-alias reordering LDS ops across the phase boundary; lgkmcnt(0)
// + sched_barrier pin the hardware/scheduler side (rule #18).
__device__ __forceinline__ void lds_fence() {
    asm volatile("s_waitcnt lgkmcnt(0)" ::: "memory");
    __builtin_amdgcn_sched_barrier(0);
}

// ---------------------------------------------------------------------------
// Pack weights to bf16 with MFMA-friendly k-order (runs once, ~3 us).
// Hidden: wp[row][k'] with k' = kk*16 + i  (tap-major!), row = (l*96+g)*16+o.
// Out:   wpo[(g*16+m)*32 + k] = w_out[g][m][k] for m<12,k<16 else 0.
// ---------------------------------------------------------------------------
__global__ __launch_bounds__(256) void navar_pack(
        const float* __restrict__ w_h, const float* __restrict__ w_out,
        unsigned short* __restrict__ wp, unsigned short* __restrict__ wpo) {
    const int e = blockIdx.x * 256 + threadIdx.x;   // grid covers NWH+NWO exactly
    if (e < NWH) {
        const int k  = e & 63, row = e >> 6;
        const int kk = k >> 4, i = k & 15;
        wp[e] = f2bf(w_h[(row << 6) + i * 4 + kk]);
    } else {
        const int e2 = e - NWH;
        const int k = e2 & 31, m = (e2 >> 5) & 15, g = e2 >> 9;
        wpo[e2] = (k < 16 && m < 12) ? f2bf(w_out[(g * NVAR + m) * HIDDEN + k])
                                     : (unsigned short)0;
    }
}

// ---------------------------------------------------------------------------
// One hidden layer (16->16, kernel 4, dilation D) for ONE WAVE's WPOS
// positions, IN-PLACE in the wave's LDS region. Read-all-then-write-all:
// every ds_read (rows <= pos) issued before any overlapping write; NT=8
// accumulators in registers (statically indexed, rule #20).
// hw points at the wave's region; pos-d may go to -12, which lands in the
// PREVIOUS wave's top rows (or the head pad for wave 0) -- any finite/NaN
// bf16 there is harmless: only positions pos<d (< the per-layer validity
// thresholds 3/6/12) read those rows, and garbage is column-confined
// (MFMA cols = positions), so no stored output is contaminated.
// ---------------------------------------------------------------------------
template<int D, int NT>
__device__ __forceinline__ void mfma_layer(
        unsigned short (*hbw)[ROWCH],        // NO restrict: src == dst
        const bf16x8 a0, const bf16x8 a1, const f32x4 bias,
        int W0, int q, int c) {
    const int ch = (q & 1) * 8;            // channel half this q supplies
    const int d0 = (3 - (q >> 1)) * D;     // tap offset, MFMA#0 (kk = q>>1)
    const int d1 = (1 - (q >> 1)) * D;     // tap offset, MFMA#1 (kk = 2+(q>>1))

    f32x4 acc[NT];
    #pragma unroll
    for (int tt = 0; tt < NT; ++tt) {      // all reads + MFMAs first
        const int pos = tt * 16 + c;       // 0..WPOS-1
        const bf16x8 b0 = *(const bf16x8*)&hbw[pos - d0][ch];
        const bf16x8 b1 = *(const bf16x8*)&hbw[pos - d1][ch];
        acc[tt] = bias;
        acc[tt] = __builtin_amdgcn_mfma_f32_16x16x32_bf16(a0, b0, acc[tt], 0, 0, 0);
        acc[tt] = __builtin_amdgcn_mfma_f32_16x16x32_bf16(a1, b1, acc[tt], 0, 0, 0);
    }
    asm volatile("" ::: "memory");         // reads stay above writes
    #pragma unroll
    for (int tt = 0; tt < NT; ++tt) {      // all writes after
        const int pos = tt * 16 + c;
        const int tgp = W0 + pos - WHALO;  // causal zero-pad
        uint2 pku;
        pku.x = cvtpk(fmaxf(acc[tt][0], 0.f), fmaxf(acc[tt][1], 0.f));
        pku.y = cvtpk(fmaxf(acc[tt][2], 0.f), fmaxf(acc[tt][3], 0.f));
        if (tgp < 0) { pku.x = 0u; pku.y = 0u; }
        *(uint2*)&hbw[pos][q * 4] = pku;   // ds_write_b64
    }
}

// ---------------------------------------------------------------------------
// BARRIER-FREE main, PACKED per-wave LDS regions (in-place layers), 128-pos
// wave tiles. Wave regions are contiguous (no per-wave pad): only ONE 16-row
// pad at the array head. LDS = (16 + 4*128) * 24 * 2 = 25344 B -> 6 blocks/CU
// (24 waves, +20% vs R8's 5 blocks) at zero extra instructions; R7 showed
// occupancy (realized 49%) is the binding constraint at this work shape.
// ---------------------------------------------------------------------------
__global__ __launch_bounds__(256, 6) void navar_main(
        const float* __restrict__ x,
        const float* __restrict__ w_in,  const float* __restrict__ b_in,
        const unsigned short* __restrict__ wp, const float* __restrict__ b_h,
        const unsigned short* __restrict__ wpo, const float* __restrict__ b_out,
        float* __restrict__ contrib) {
    __shared__ unsigned short hb[WPAD + 4 * WPOS][ROWCH];   // 528 rows, packed

    const int p    = threadIdx.x;
    const int wave = p >> 6, lane = p & 63;
    const int q    = lane >> 4, c = lane & 15;
    const int bt   = blockIdx.x % NBT;
    const int sg   = blockIdx.x / NBT;
    const int b    = sg / NGROUPS;
    const int g    = sg % NGROUPS;
    const int tw   = bt * 4 + wave;        // 0..19
    const int W0   = tw * WOUT;            // first output t of this wave

    unsigned short (*hw)[ROWCH] =
        (unsigned short (*)[ROWCH])&hb[WPAD + wave * WPOS];   // wave region

    // ---- MFMA operand loads (coalesced packed bf16; compiler sinks these
    //      into the layers as needed -- R7 showed VGPR=40, loads sunk) ----
    const size_t wstep = (size_t)NGROUPS * HIDDEN * (HIDDEN * KSZ);
    const unsigned short* wr0 =
        wp + (size_t)(g * HIDDEN + c) * (HIDDEN * KSZ);
    bf16x8 A0[3], A1[3]; f32x4 BH[3];
    #pragma unroll
    for (int l = 0; l < 3; ++l) {
        A0[l] = *(const bf16x8*)(wr0 + l * wstep + q * 8);        // k' = q*8+j
        A1[l] = *(const bf16x8*)(wr0 + l * wstep + 32 + q * 8);   // k' = 32+q*8+j
        BH[l] = *(const f32x4*)(b_h + (l * NGROUPS + g) * HIDDEN + q * 4);
    }
    const unsigned short* wrowo = wpo + (size_t)(g * HIDDEN + c) * 32;
    const bf16x8 AO = *(const bf16x8*)(wrowo + q * 8);            // zeros q>=2
    f32x4 BO = {0.f, 0.f, 0.f, 0.f};
    if (q < 3) BO = *(const f32x4*)(b_out + g * NVAR + q * 4);

    // ---- x load + input conv 1->16 fp32, two 64-row chunks ----
    // row = k*64 + lane; global t = W0 + row - WHALO.
    const size_t xrow = (size_t)(b * NGROUPS + g) * T_LEN;
    const float* w  = w_in + g * HIDDEN * KSZ;       // block-uniform -> s_load
    const float* bb = b_in + g * HIDDEN;
    #pragma unroll
    for (int k = 0; k < 2; ++k) {
        const int row = k * 64 + lane;
        const int gx  = W0 + row - WHALO;
        const float xv = (gx >= 0 && gx < T_LEN) ? x[xrow + gx] : 0.f;
        float t2 = __shfl_up(xv, 1);       // all lanes execute the shuffles
        float t1 = __shfl_up(xv, 2);
        float t0 = __shfl_up(xv, 3);
        if (k == 1 || lane >= 3) {         // k=0 lanes 0..2: never-valid rows
            if (lane < 3) {                // chunk-boundary lanes: refetch
                t0 = (gx >= 3 && gx - 3 < T_LEN) ? x[xrow + gx - 3] : 0.f;
                t1 = (gx >= 2 && gx - 2 < T_LEN) ? x[xrow + gx - 2] : 0.f;
                t2 = (gx >= 1 && gx - 1 < T_LEN) ? x[xrow + gx - 1] : 0.f;
            }
            const float t3 = xv;
            unsigned pk[8];
            #pragma unroll
            for (int o = 0; o < HIDDEN; o += 2) {
                float e0 = fmaf(w[o*4+0], t0, bb[o]);
                e0 = fmaf(w[o*4+1], t1, e0);
                e0 = fmaf(w[o*4+2], t2, e0);
                e0 = fmaf(w[o*4+3], t3, e0);
                float e1 = fmaf(w[o*4+4], t0, bb[o+1]);
                e1 = fmaf(w[o*4+5], t1, e1);
                e1 = fmaf(w[o*4+6], t2, e1);
                e1 = fmaf(w[o*4+7], t3, e1);
                const unsigned u = cvtpk(fmaxf(e0, 0.f), fmaxf(e1, 0.f));
                pk[o >> 1] = (gx >= 0) ? u : 0u;      // causal zero-pad
            }
            uint4* rowp = (uint4*)&hw[row][0];
            rowp[0] = make_uint4(pk[0], pk[1], pk[2], pk[3]);
            rowp[1] = make_uint4(pk[4], pk[5], pk[6], pk[7]);
        }
    }
    lds_fence();

    // ---- 3 dilated hidden blocks via MFMA (in-place, no barriers) ----
    mfma_layer<1, 8>(hw, A0[0], A1[0], BH[0], W0, q, c);
    lds_fence();
    mfma_layer<2, 8>(hw, A0[1], A1[1], BH[1], W0, q, c);
    lds_fence();
    mfma_layer<4, 8>(hw, A0[2], A1[2], BH[2], W0, q, c);
    lds_fence();

    // ---- output 1x1 conv 16->12 as one MFMA per subtile ----
    {
        const int gds = g / NVAR, srcv = g % NVAR;
        #pragma unroll
        for (int tt = 0; tt < 8; ++tt) {
            const int pos = tt * 16 + c;
            const bf16x8 b0 = *(const bf16x8*)&hw[pos][(q & 1) * 8];
            f32x4 acc = BO;
            acc = __builtin_amdgcn_mfma_f32_16x16x32_bf16(AO, b0, acc, 0, 0, 0);
            const int t = W0 + pos - WHALO;
            if (q < 3 && pos >= WHALO && t < T_LEN) {
                const size_t base =
                    (((size_t)b * NGROUPS + gds * NVAR) * NVAR + srcv) * T_LEN + t;
                #pragma unroll
                for (int r = 0; r < 4; ++r)   // v = q*4+r; lanes c -> coalesced t
                    contrib[base + (size_t)(q * 4 + r) * NVAR * T_LEN] = acc[r];
            }
        }
    }
}

// ---------------------------------------------------------------------------
// prediction[b,ds,v,t] = biases[ds,v] + sum_src contrib[b,ds,v,src,t]
// (reads 75 MB + writes 6 MB in ~13 us ~= HBM roofline; leave alone)
// ---------------------------------------------------------------------------
__global__ __launch_bounds__(256) void navar_pred(
        const float* __restrict__ contrib, const float* __restrict__ biases,
        float* __restrict__ pred) {
    const int e = (blockIdx.x * 256 + threadIdx.x) * 4;
    const int t = e % T_LEN;
    const int G = e / T_LEN;
    const float4* c = (const float4*)(contrib + (size_t)G * NVAR * T_LEN + t);
    const float bias = biases[G % NGROUPS];
    float4 acc = make_float4(bias, bias, bias, bias);
    #pragma unroll
    for (int s = 0; s < NVAR; ++s) {
        float4 v = c[(size_t)s * (T_LEN / 4)];
        acc.x += v.x; acc.y += v.y; acc.z += v.z; acc.w += v.w;
    }
    *(float4*)(pred + e) = acc;
}

extern "C" void kernel_launch(void* const* d_in, const int* in_sizes, int n_in,
                              void* d_out, int out_size, void* d_ws, size_t ws_size,
                              hipStream_t stream) {
    const float* x      = (const float*)d_in[0];
    const float* w_in   = (const float*)d_in[1];
    const float* b_in   = (const float*)d_in[2];
    const float* w_h    = (const float*)d_in[3];
    const float* b_h    = (const float*)d_in[4];
    const float* w_out  = (const float*)d_in[5];
    const float* b_out  = (const float*)d_in[6];
    const float* biases = (const float*)d_in[7];

    float* pred    = (float*)d_out;                               // 8*96*2048 floats
    float* contrib = pred + (size_t)BATCH * NGROUPS * T_LEN;      // 8*96*12*2048 floats
    unsigned short* wp  = (unsigned short*)d_ws;                  // NWH bf16
    unsigned short* wpo = wp + NWH;                               // NWO bf16

    // pack hidden + output weights to bf16 (k-reordered)
    navar_pack<<<(NWH + NWO) / 256, 256, 0, stream>>>(w_h, w_out, wp, wpo);
    // main: one block per (batch, group, 4-wave tile chunk)
    navar_main<<<BATCH * NGROUPS * NBT, 256, 0, stream>>>(
        x, w_in, b_in, wp, b_h, wpo, b_out, contrib);
    // prediction reduction: BATCH*NGROUPS*T_LEN / (256*4) = 1536 blocks
    navar_pred<<<(BATCH * NGROUPS * T_LEN) / (256 * 4), 256, 0, stream>>>(
        contrib, biases, pred);
}

// Round 10
// 137.757 us; speedup vs baseline: 1.0924x; 1.0924x over previous
//
#include <hip/hip_runtime.h>

// NAVAR dims (fixed by the problem)
#define T_LEN   2048
#define BATCH   8
#define HIDDEN  16
#define KSZ     4
#define NVAR    12
#define NGROUPS 96      // ND*NS*NV = 2*4*12

// Wave-autonomous tiling: each WAVE owns 104 outputs + private 24-halo.
#define WOUT  104             // useful outputs per wave
#define WHALO 24              // 3*(1+1+2+4) receptive-field halo
#define WPOS  128             // positions computed per wave (2 x 64 lanes)
#define WPAD  16              // pad rows at ARRAY HEAD only (see hb note)
#define ROWCH 24              // 16 ch + 8 pad (48 B rows, 16-B aligned, 2-way banks)
#define NBT   5               // blocks along T (4 waves * 104 = 416; 5*416=2080)

#define NWH  (3 * NGROUPS * HIDDEN * HIDDEN * KSZ)   // 294912 hidden weights
#define NWO  (NGROUPS * HIDDEN * 32)                 // 49152 padded out weights

typedef __attribute__((ext_vector_type(8))) short bf16x8;   // MFMA A/B frag
typedef __attribute__((ext_vector_type(4))) float f32x4;    // MFMA C/D frag

__device__ __forceinline__ unsigned short f2bf(float x) {   // fp32 -> bf16 RNE
    union { float f; unsigned u; } v; v.f = x;
    unsigned r = v.u + 0x7FFFu + ((v.u >> 16) & 1u);
    return (unsigned short)(r >> 16);
}

// fp32 pair -> packed bf16x2 via HW RNE convert (same rounding as f2bf;
// verified R4/R5: absmax unchanged).
__device__ __forceinline__ unsigned cvtpk(float lo, float hi) {
    unsigned r;
    asm("v_cvt_pk_bf16_f32 %0, %1, %2" : "=v"(r) : "v"(lo), "v"(hi));
    return r;
}

// Wave-level LDS phase fence: memory clobber stops the compiler from
// per-lane-alias reordering LDS ops across the phase boundary; lgkmcnt(0)
// + sched_barrier pin the hardware/scheduler side (rule #18).
__device__ __forceinline__ void lds_fence() {
    asm volatile("s_waitcnt lgkmcnt(0)" ::: "memory");
    __builtin_amdgcn_sched_barrier(0);
}

// ---------------------------------------------------------------------------
// Pack weights to bf16 with MFMA-friendly k-order (runs once, ~3 us).
// Hidden: wp[row][k'] with k' = kk*16 + i  (tap-major!), row = (l*96+g)*16+o.
// Out:   wpo[(g*16+m)*32 + k] = w_out[g][m][k] for m<12,k<16 else 0.
// ---------------------------------------------------------------------------
__global__ __launch_bounds__(256) void navar_pack(
        const float* __restrict__ w_h, const float* __restrict__ w_out,
        unsigned short* __restrict__ wp, unsigned short* __restrict__ wpo) {
    const int e = blockIdx.x * 256 + threadIdx.x;   // grid covers NWH+NWO exactly
    if (e < NWH) {
        const int k  = e & 63, row = e >> 6;
        const int kk = k >> 4, i = k & 15;
        wp[e] = f2bf(w_h[(row << 6) + i * 4 + kk]);
    } else {
        const int e2 = e - NWH;
        const int k = e2 & 31, m = (e2 >> 5) & 15, g = e2 >> 9;
        wpo[e2] = (k < 16 && m < 12) ? f2bf(w_out[(g * NVAR + m) * HIDDEN + k])
                                     : (unsigned short)0;
    }
}

// ---------------------------------------------------------------------------
// One hidden layer (16->16, kernel 4, dilation D) for ONE WAVE's WPOS
// positions, IN-PLACE in the wave's LDS region. Read-all-then-write-all:
// every ds_read (rows <= pos) issued before any overlapping write; NT=8
// accumulators in registers (statically indexed, rule #20).
// hw points at the wave's region; pos-d may go to -12, which lands in the
// PREVIOUS wave's top rows (or the head pad for wave 0) -- any finite/NaN
// bf16 there is harmless: only positions pos<d (< the per-layer validity
// thresholds 3/6/12) read those rows, and garbage is column-confined
// (MFMA cols = positions), so no stored output is contaminated.
// ---------------------------------------------------------------------------
template<int D, int NT>
__device__ __forceinline__ void mfma_layer(
        unsigned short (*hbw)[ROWCH],        // NO restrict: src == dst
        const bf16x8 a0, const bf16x8 a1, const f32x4 bias,
        int W0, int q, int c) {
    const int ch = (q & 1) * 8;            // channel half this q supplies
    const int d0 = (3 - (q >> 1)) * D;     // tap offset, MFMA#0 (kk = q>>1)
    const int d1 = (1 - (q >> 1)) * D;     // tap offset, MFMA#1 (kk = 2+(q>>1))

    f32x4 acc[NT];
    #pragma unroll
    for (int tt = 0; tt < NT; ++tt) {      // all reads + MFMAs first
        const int pos = tt * 16 + c;       // 0..WPOS-1
        const bf16x8 b0 = *(const bf16x8*)&hbw[pos - d0][ch];
        const bf16x8 b1 = *(const bf16x8*)&hbw[pos - d1][ch];
        acc[tt] = bias;
        acc[tt] = __builtin_amdgcn_mfma_f32_16x16x32_bf16(a0, b0, acc[tt], 0, 0, 0);
        acc[tt] = __builtin_amdgcn_mfma_f32_16x16x32_bf16(a1, b1, acc[tt], 0, 0, 0);
    }
    asm volatile("" ::: "memory");         // reads stay above writes
    #pragma unroll
    for (int tt = 0; tt < NT; ++tt) {      // all writes after
        const int pos = tt * 16 + c;
        const int tgp = W0 + pos - WHALO;  // causal zero-pad
        uint2 pku;
        pku.x = cvtpk(fmaxf(acc[tt][0], 0.f), fmaxf(acc[tt][1], 0.f));
        pku.y = cvtpk(fmaxf(acc[tt][2], 0.f), fmaxf(acc[tt][3], 0.f));
        if (tgp < 0) { pku.x = 0u; pku.y = 0u; }
        *(uint2*)&hbw[pos][q * 4] = pku;   // ds_write_b64
    }
}

// ---------------------------------------------------------------------------
// BARRIER-FREE main, PACKED per-wave LDS regions (in-place layers), 128-pos
// wave tiles. Wave regions contiguous; single 16-row pad at array head.
// LDS = (16 + 4*128) * 24 * 2 = 25344 B -> LDS permits 6 blocks/CU.
// __launch_bounds__(256,5) (NOT 6): let the compiler allocate VGPRs
// naturally (~72-80 expected); if <=85, HW still places 6 blocks
// (6 blk * 4 waves * 85 VGPR = 510/SIMD <= 512; LDS 152K <= 160K) --
// R9's forced (256,6) risked spills for the same residency.
// ---------------------------------------------------------------------------
__global__ __launch_bounds__(256, 5) void navar_main(
        const float* __restrict__ x,
        const float* __restrict__ w_in,  const float* __restrict__ b_in,
        const unsigned short* __restrict__ wp, const float* __restrict__ b_h,
        const unsigned short* __restrict__ wpo, const float* __restrict__ b_out,
        float* __restrict__ contrib) {
    __shared__ unsigned short hb[WPAD + 4 * WPOS][ROWCH];   // 528 rows, packed

    const int p    = threadIdx.x;
    const int wave = p >> 6, lane = p & 63;
    const int q    = lane >> 4, c = lane & 15;
    const int bt   = blockIdx.x % NBT;
    const int sg   = blockIdx.x / NBT;
    const int b    = sg / NGROUPS;
    const int g    = sg % NGROUPS;
    const int tw   = bt * 4 + wave;        // 0..19
    const int W0   = tw * WOUT;            // first output t of this wave

    unsigned short (*hw)[ROWCH] =
        (unsigned short (*)[ROWCH])&hb[WPAD + wave * WPOS];   // wave region

    // ---- MFMA operand loads (coalesced packed bf16; compiler sinks these
    //      into the layers as needed -- R7 showed VGPR=40, loads sunk) ----
    const size_t wstep = (size_t)NGROUPS * HIDDEN * (HIDDEN * KSZ);
    const unsigned short* wr0 =
        wp + (size_t)(g * HIDDEN + c) * (HIDDEN * KSZ);
    bf16x8 A0[3], A1[3]; f32x4 BH[3];
    #pragma unroll
    for (int l = 0; l < 3; ++l) {
        A0[l] = *(const bf16x8*)(wr0 + l * wstep + q * 8);        // k' = q*8+j
        A1[l] = *(const bf16x8*)(wr0 + l * wstep + 32 + q * 8);   // k' = 32+q*8+j
        BH[l] = *(const f32x4*)(b_h + (l * NGROUPS + g) * HIDDEN + q * 4);
    }
    const unsigned short* wrowo = wpo + (size_t)(g * HIDDEN + c) * 32;
    const bf16x8 AO = *(const bf16x8*)(wrowo + q * 8);            // zeros q>=2
    f32x4 BO = {0.f, 0.f, 0.f, 0.f};
    if (q < 3) BO = *(const f32x4*)(b_out + g * NVAR + q * 4);

    // ---- x load + input conv 1->16 fp32, two 64-row chunks ----
    // row = k*64 + lane; global t = W0 + row - WHALO.
    const size_t xrow = (size_t)(b * NGROUPS + g) * T_LEN;
    const float* w  = w_in + g * HIDDEN * KSZ;       // block-uniform -> s_load
    const float* bb = b_in + g * HIDDEN;
    #pragma unroll
    for (int k = 0; k < 2; ++k) {
        const int row = k * 64 + lane;
        const int gx  = W0 + row - WHALO;
        const float xv = (gx >= 0 && gx < T_LEN) ? x[xrow + gx] : 0.f;
        float t2 = __shfl_up(xv, 1);       // all lanes execute the shuffles
        float t1 = __shfl_up(xv, 2);
        float t0 = __shfl_up(xv, 3);
        if (k == 1 || lane >= 3) {         // k=0 lanes 0..2: never-valid rows
            if (lane < 3) {                // chunk-boundary lanes: refetch
                t0 = (gx >= 3 && gx - 3 < T_LEN) ? x[xrow + gx - 3] : 0.f;
                t1 = (gx >= 2 && gx - 2 < T_LEN) ? x[xrow + gx - 2] : 0.f;
                t2 = (gx >= 1 && gx - 1 < T_LEN) ? x[xrow + gx - 1] : 0.f;
            }
            const float t3 = xv;
            unsigned pk[8];
            #pragma unroll
            for (int o = 0; o < HIDDEN; o += 2) {
                float e0 = fmaf(w[o*4+0], t0, bb[o]);
                e0 = fmaf(w[o*4+1], t1, e0);
                e0 = fmaf(w[o*4+2], t2, e0);
                e0 = fmaf(w[o*4+3], t3, e0);
                float e1 = fmaf(w[o*4+4], t0, bb[o+1]);
                e1 = fmaf(w[o*4+5], t1, e1);
                e1 = fmaf(w[o*4+6], t2, e1);
                e1 = fmaf(w[o*4+7], t3, e1);
                const unsigned u = cvtpk(fmaxf(e0, 0.f), fmaxf(e1, 0.f));
                pk[o >> 1] = (gx >= 0) ? u : 0u;      // causal zero-pad
            }
            uint4* rowp = (uint4*)&hw[row][0];
            rowp[0] = make_uint4(pk[0], pk[1], pk[2], pk[3]);
            rowp[1] = make_uint4(pk[4], pk[5], pk[6], pk[7]);
        }
    }
    lds_fence();

    // ---- 3 dilated hidden blocks via MFMA (in-place, no barriers) ----
    mfma_layer<1, 8>(hw, A0[0], A1[0], BH[0], W0, q, c);
    lds_fence();
    mfma_layer<2, 8>(hw, A0[1], A1[1], BH[1], W0, q, c);
    lds_fence();
    mfma_layer<4, 8>(hw, A0[2], A1[2], BH[2], W0, q, c);
    lds_fence();

    // ---- output 1x1 conv 16->12 as one MFMA per subtile ----
    {
        const int gds = g / NVAR, srcv = g % NVAR;
        #pragma unroll
        for (int tt = 0; tt < 8; ++tt) {
            const int pos = tt * 16 + c;
            const bf16x8 b0 = *(const bf16x8*)&hw[pos][(q & 1) * 8];
            f32x4 acc = BO;
            acc = __builtin_amdgcn_mfma_f32_16x16x32_bf16(AO, b0, acc, 0, 0, 0);
            const int t = W0 + pos - WHALO;
            if (q < 3 && pos >= WHALO && t < T_LEN) {
                const size_t base =
                    (((size_t)b * NGROUPS + gds * NVAR) * NVAR + srcv) * T_LEN + t;
                #pragma unroll
                for (int r = 0; r < 4; ++r)   // v = q*4+r; lanes c -> coalesced t
                    contrib[base + (size_t)(q * 4 + r) * NVAR * T_LEN] = acc[r];
            }
        }
    }
}

// ---------------------------------------------------------------------------
// prediction[b,ds,v,t] = biases[ds,v] + sum_src contrib[b,ds,v,src,t]
// (reads 75 MB + writes 6 MB in ~13 us ~= HBM roofline; leave alone)
// ---------------------------------------------------------------------------
__global__ __launch_bounds__(256) void navar_pred(
        const float* __restrict__ contrib, const float* __restrict__ biases,
        float* __restrict__ pred) {
    const int e = (blockIdx.x * 256 + threadIdx.x) * 4;
    const int t = e % T_LEN;
    const int G = e / T_LEN;
    const float4* c = (const float4*)(contrib + (size_t)G * NVAR * T_LEN + t);
    const float bias = biases[G % NGROUPS];
    float4 acc = make_float4(bias, bias, bias, bias);
    #pragma unroll
    for (int s = 0; s < NVAR; ++s) {
        float4 v = c[(size_t)s * (T_LEN / 4)];
        acc.x += v.x; acc.y += v.y; acc.z += v.z; acc.w += v.w;
    }
    *(float4*)(pred + e) = acc;
}

extern "C" void kernel_launch(void* const* d_in, const int* in_sizes, int n_in,
                              void* d_out, int out_size, void* d_ws, size_t ws_size,
                              hipStream_t stream) {
    const float* x      = (const float*)d_in[0];
    const float* w_in   = (const float*)d_in[1];
    const float* b_in   = (const float*)d_in[2];
    const float* w_h    = (const float*)d_in[3];
    const float* b_h    = (const float*)d_in[4];
    const float* w_out  = (const float*)d_in[5];
    const float* b_out  = (const float*)d_in[6];
    const float* biases = (const float*)d_in[7];

    float* pred    = (float*)d_out;                               // 8*96*2048 floats
    float* contrib = pred + (size_t)BATCH * NGROUPS * T_LEN;      // 8*96*12*2048 floats
    unsigned short* wp  = (unsigned short*)d_ws;                  // NWH bf16
    unsigned short* wpo = wp + NWH;                               // NWO bf16

    // pack hidden + output weights to bf16 (k-reordered)
    navar_pack<<<(NWH + NWO) / 256, 256, 0, stream>>>(w_h, w_out, wp, wpo);
    // main: one block per (batch, group, 4-wave tile chunk)
    navar_main<<<BATCH * NGROUPS * NBT, 256, 0, stream>>>(
        x, w_in, b_in, wp, b_h, wpo, b_out, contrib);
    // prediction reduction: BATCH*NGROUPS*T_LEN / (256*4) = 1536 blocks
    navar_pred<<<(BATCH * NGROUPS * T_LEN) / (256 * 4), 256, 0, stream>>>(
        contrib, biases, pred);
}